// Round 1
// baseline (1238.139 us; speedup 1.0000x reference)
//
#include <hip/hip_runtime.h>

// RelMultiHeadAttention (Transformer-XL) on gfx950.
// B=2, S=2048, D=1024, H=16, hd=64. All heavy math in bf16 MFMA 16x16x32.

typedef float  floatx4 __attribute__((ext_vector_type(4)));
typedef __bf16 bf16x8  __attribute__((ext_vector_type(8)));

#define LSTR 40   // LDS row stride (bf16 elems): 80B rows -> conflict-free b128 reads

struct GP {
  const void* A;
  const __bf16* B;
  long sAz, sBz;         // batch (z) strides in elements
  int lda, ldb, K;
  float* outF;
  __bf16* out1;
  __bf16* out2;
  const float* bias;
  const float* rrb;
  const float* cbv;
  float scale;
  int lo, CH;
};

// MODE: 0=Qproj(dual q/qrr) 1=Kproj 2=Vproj(transposed) 3=Rproj 4=OUTproj 5=QKscores 6=POSscatter
template<int MODE, bool AF32>
__global__ void __launch_bounds__(256) gemm_k(GP p) {
  __shared__ __bf16 lA[128 * LSTR];
  __shared__ __bf16 lB[128 * LSTR];
  const int t = threadIdx.x;
  const int wave = t >> 6, lane = t & 63;
  const int z = blockIdx.z;
  const int m0 = blockIdx.y * 128, n0 = blockIdx.x * 128;
  const int srow = t >> 2, scol = (t & 3) << 3;

  const float*  Af = (const float*)p.A;
  const __bf16* Ab = (const __bf16*)p.A;
  const long aoff = (long)z * p.sAz;
  long boff;
  if constexpr (MODE == 6) boff = (long)(z & 15) * p.sBz;  // r is per-head only
  else                     boff = (long)z * p.sBz;
  const __bf16* Bb = p.B + boff;

  floatx4 acc[4][4];
#pragma unroll
  for (int i = 0; i < 4; i++)
#pragma unroll
    for (int j = 0; j < 4; j++) acc[i][j] = floatx4{0.f, 0.f, 0.f, 0.f};

  const int lr = lane & 15, lq = lane >> 4;
  const int wr = (wave >> 1) << 6, wc = (wave & 1) << 6;

  for (int kk = 0; kk < p.K; kk += 32) {
#pragma unroll
    for (int h2 = 0; h2 < 2; h2++) {
      int r = srow + (h2 << 6);
      if (AF32) {
        const float* ap = Af + aoff + (long)(m0 + r) * p.lda + kk + scol;
        float4 f0 = *(const float4*)ap;
        float4 f1 = *(const float4*)(ap + 4);
        bf16x8 o;
        o[0] = (__bf16)f0.x; o[1] = (__bf16)f0.y; o[2] = (__bf16)f0.z; o[3] = (__bf16)f0.w;
        o[4] = (__bf16)f1.x; o[5] = (__bf16)f1.y; o[6] = (__bf16)f1.z; o[7] = (__bf16)f1.w;
        *(bf16x8*)&lA[r * LSTR + scol] = o;
      } else {
        const __bf16* ap = Ab + aoff + (long)(m0 + r) * p.lda + kk + scol;
        *(bf16x8*)&lA[r * LSTR + scol] = *(const bf16x8*)ap;
      }
      const __bf16* bp = Bb + (long)(n0 + r) * p.ldb + kk + scol;
      *(bf16x8*)&lB[r * LSTR + scol] = *(const bf16x8*)bp;
    }
    __syncthreads();
    bf16x8 aF[4], bF[4];
#pragma unroll
    for (int i = 0; i < 4; i++)
      aF[i] = *(bf16x8*)&lA[(wr + i * 16 + lr) * LSTR + (lq << 3)];
#pragma unroll
    for (int i = 0; i < 4; i++)
      bF[i] = *(bf16x8*)&lB[(wc + i * 16 + lr) * LSTR + (lq << 3)];
#pragma unroll
    for (int i = 0; i < 4; i++)
#pragma unroll
      for (int j = 0; j < 4; j++)
        acc[i][j] = __builtin_amdgcn_mfma_f32_16x16x32_bf16(aF[i], bF[j], acc[i][j], 0, 0, 0);
    __syncthreads();
  }

  // Epilogue. C/D layout: col = lane&15, row = (lane>>4)*4 + reg  [measured m89/m91]
#pragma unroll
  for (int i = 0; i < 4; i++) {
#pragma unroll
    for (int j = 0; j < 4; j++) {
      int col = n0 + wc + j * 16 + lr;
#pragma unroll
      for (int g = 0; g < 4; g++) {
        int rl = m0 + wr + i * 16 + (lq << 2) + g;
        float val = acc[i][j][g];
        if constexpr (MODE <= 2) {
          int b = rl >> 11, s = rl & 2047;
          int h = col >> 6, d = col & 63;
          float v = val + p.bias[col];
          if constexpr (MODE == 0) {
            long dst = (((long)(b * 16 + h) * 2048 + s) << 6) + d;
            p.out1[dst] = (__bf16)v;
            p.out2[dst] = (__bf16)(v + p.rrb[col]);
          } else if constexpr (MODE == 1) {
            long dst = (((long)(b * 16 + h) * 2048 + s) << 6) + d;
            p.out1[dst] = (__bf16)v;
          } else {  // V transposed: [bh][d][seq]
            long dst = ((((long)(b * 16 + h)) << 6) + d) * 2048 + s;
            p.out1[dst] = (__bf16)v;
          }
        } else if constexpr (MODE == 3) {
          int h = col >> 6, d = col & 63;
          long dst = (((long)h * 2048 + rl) << 6) + d;
          p.out1[dst] = (__bf16)val;
        } else if constexpr (MODE == 4) {
          p.outF[(long)rl * 1024 + col] = val + p.bias[col];
        } else if constexpr (MODE == 5) {
          p.outF[((long)z * p.CH + rl) * 2048 + col] = val * p.scale + p.cbv[z * 2048 + col];
        } else if constexpr (MODE == 6) {
          // x[a,m] -> rel-shifted destination (bijective; j=i+1 stays untouched = 0 pos)
          int a = p.lo + rl;
          float v = val * p.scale;
          long base = (long)z * p.CH * 2048;
          if (col >= 2047 - a) {          // case j<=i: i=a, j=m-2047+a
            p.outF[base + (long)rl * 2048 + (col - 2047 + a)] += v;
          } else if (rl >= 1) {           // case j>i+1: i=a-1, j=m+a+1
            p.outF[base + (long)(rl - 1) * 2048 + (col + a + 1)] += v;
          }
        }
      }
    }
  }
}

// extra row a = lo+CH: case2 contributions to chunk's last row (i = lo+CH-1, j >= lo+CH+1)
__global__ void __launch_bounds__(256) pos_extra(const __bf16* qrr, const __bf16* rb,
                                                 float* scores, int lo, int CH) {
  const int z = blockIdx.y;
  const int h = z & 15;
  const int a = lo + CH;
  __shared__ float qa[64];
  if (threadIdx.x < 64)
    qa[threadIdx.x] = (float)qrr[(((long)z * 2048 + a) << 6) + threadIdx.x];
  __syncthreads();
  int m = blockIdx.x * 256 + threadIdx.x;
  if (m <= 2046 - a) {
    const __bf16* rp = rb + (((long)h * 2048 + m) << 6);
    float s = 0.f;
#pragma unroll
    for (int c = 0; c < 8; c++) {
      bf16x8 rv = *(const bf16x8*)(rp + c * 8);
#pragma unroll
      for (int e = 0; e < 8; e++) s += qa[c * 8 + e] * (float)rv[e];
    }
    scores[((long)z * CH + (CH - 1)) * 2048 + (m + a + 1)] += s * 0.125f;
  }
}

__global__ void __launch_bounds__(256) cb_k(const __bf16* kb, const float* rwb, float* cb) {
  long id = (long)blockIdx.x * 256 + threadIdx.x;  // 32*2048
  int z = (int)(id >> 11);
  int j = (int)(id & 2047);
  int h = z & 15;
  const __bf16* kp = kb + (((long)z * 2048 + j) << 6);
  float s = 0.f;
#pragma unroll
  for (int c = 0; c < 8; c++) {
    bf16x8 kv = *(const bf16x8*)(kp + c * 8);
#pragma unroll
    for (int e = 0; e < 8; e++) s += rwb[h * 64 + c * 8 + e] * (float)kv[e];
  }
  cb[id] = s * 0.125f;
}

__global__ void __launch_bounds__(256) tr_cvt(const float* src, __bf16* dst) {
  __shared__ float tile[64][65];
  int bx = blockIdx.x, by = blockIdx.y;
  int tx = threadIdx.x & 63, ty = threadIdx.x >> 6;
#pragma unroll
  for (int r = ty; r < 64; r += 4)
    tile[r][tx] = src[(long)(by * 64 + r) * 1024 + bx * 64 + tx];
  __syncthreads();
#pragma unroll
  for (int r = ty; r < 64; r += 4)
    dst[(long)(bx * 64 + r) * 1024 + by * 64 + tx] = (__bf16)tile[tx][r];
}

__global__ void __launch_bounds__(256) softmax_k(float* sc) {
  float* pr = sc + (long)blockIdx.x * 2048;
  int t = threadIdx.x;
  float4 a  = *(float4*)(pr + t * 8);
  float4 b4 = *(float4*)(pr + t * 8 + 4);
  float mx = fmaxf(fmaxf(fmaxf(a.x, a.y), fmaxf(a.z, a.w)),
                   fmaxf(fmaxf(b4.x, b4.y), fmaxf(b4.z, b4.w)));
#pragma unroll
  for (int o = 32; o > 0; o >>= 1) mx = fmaxf(mx, __shfl_down(mx, o, 64));
  __shared__ float red[4], red2[4];
  if ((t & 63) == 0) red[t >> 6] = mx;
  __syncthreads();
  mx = fmaxf(fmaxf(red[0], red[1]), fmaxf(red[2], red[3]));
  a.x = __expf(a.x - mx); a.y = __expf(a.y - mx); a.z = __expf(a.z - mx); a.w = __expf(a.w - mx);
  b4.x = __expf(b4.x - mx); b4.y = __expf(b4.y - mx); b4.z = __expf(b4.z - mx); b4.w = __expf(b4.w - mx);
  float s = a.x + a.y + a.z + a.w + b4.x + b4.y + b4.z + b4.w;
#pragma unroll
  for (int o = 32; o > 0; o >>= 1) s += __shfl_down(s, o, 64);
  if ((t & 63) == 0) red2[t >> 6] = s;
  __syncthreads();
  s = red2[0] + red2[1] + red2[2] + red2[3];
  float inv = 1.0f / s;
  a.x *= inv; a.y *= inv; a.z *= inv; a.w *= inv;
  b4.x *= inv; b4.y *= inv; b4.z *= inv; b4.w *= inv;
  *(float4*)(pr + t * 8) = a;
  *(float4*)(pr + t * 8 + 4) = b4;
}

// PV: attn[b, lo+i, h*64+d] += probs[z,i,:] @ v[z,:,d], split-K over 8 segments of 256
__global__ void __launch_bounds__(256) pv_k(const float* probs, const __bf16* vt,
                                            float* attn, int lo, int CH) {
  __shared__ __bf16 lA[128 * LSTR];
  __shared__ __bf16 lB[64 * LSTR];
  const int t = threadIdx.x;
  const int wave = t >> 6, lane = t & 63;
  const int z = blockIdx.z;
  const int seg = blockIdx.x;
  const int m0 = blockIdx.y * 128;
  const int b = z >> 4, h = z & 15;
  const int srow = t >> 2, scol = (t & 3) << 3;
  const float*  A = probs + ((long)z * CH + m0) * 2048 + seg * 256;
  const __bf16* B = vt + ((long)z << 6) * 2048 + seg * 256;

  floatx4 acc[2][4];
#pragma unroll
  for (int i = 0; i < 2; i++)
#pragma unroll
    for (int j = 0; j < 4; j++) acc[i][j] = floatx4{0.f, 0.f, 0.f, 0.f};

  const int lr = lane & 15, lq = lane >> 4;
  const int wr = wave << 5;

  for (int kk = 0; kk < 256; kk += 32) {
#pragma unroll
    for (int h2 = 0; h2 < 2; h2++) {
      int r = srow + (h2 << 6);
      const float* ap = A + (long)r * 2048 + kk + scol;
      float4 f0 = *(const float4*)ap;
      float4 f1 = *(const float4*)(ap + 4);
      bf16x8 o;
      o[0] = (__bf16)f0.x; o[1] = (__bf16)f0.y; o[2] = (__bf16)f0.z; o[3] = (__bf16)f0.w;
      o[4] = (__bf16)f1.x; o[5] = (__bf16)f1.y; o[6] = (__bf16)f1.z; o[7] = (__bf16)f1.w;
      *(bf16x8*)&lA[r * LSTR + scol] = o;
    }
    {
      const __bf16* bp = B + (long)srow * 2048 + kk + scol;
      *(bf16x8*)&lB[srow * LSTR + scol] = *(const bf16x8*)bp;
    }
    __syncthreads();
    bf16x8 aF[2], bF[4];
#pragma unroll
    for (int i = 0; i < 2; i++)
      aF[i] = *(bf16x8*)&lA[(wr + i * 16 + lr) * LSTR + (lq << 3)];
#pragma unroll
    for (int j = 0; j < 4; j++)
      bF[j] = *(bf16x8*)&lB[(j * 16 + lr) * LSTR + (lq << 3)];
#pragma unroll
    for (int i = 0; i < 2; i++)
#pragma unroll
      for (int j = 0; j < 4; j++)
        acc[i][j] = __builtin_amdgcn_mfma_f32_16x16x32_bf16(aF[i], bF[j], acc[i][j], 0, 0, 0);
    __syncthreads();
  }
#pragma unroll
  for (int i = 0; i < 2; i++)
#pragma unroll
    for (int j = 0; j < 4; j++)
#pragma unroll
      for (int g = 0; g < 4; g++) {
        int rl = m0 + wr + i * 16 + (lq << 2) + g;
        int col = j * 16 + lr;
        unsafeAtomicAdd(&attn[((long)b * 2048 + lo + rl) * 1024 + h * 64 + col],
                        acc[i][j][g]);
      }
}

extern "C" void kernel_launch(void* const* d_in, const int* in_sizes, int n_in,
                              void* d_out, int out_size, void* d_ws, size_t ws_size,
                              hipStream_t stream) {
  (void)in_sizes; (void)n_in; (void)out_size;
  const float* inputs_kv = (const float*)d_in[0];
  const float* inputs_q  = (const float*)d_in[1];
  const float* pos_embed = (const float*)d_in[2];
  const float* Wq_w = (const float*)d_in[3];
  const float* Wq_b = (const float*)d_in[4];
  const float* Wk_w = (const float*)d_in[5];
  const float* Wk_b = (const float*)d_in[6];
  const float* Wv_w = (const float*)d_in[7];
  const float* Wv_b = (const float*)d_in[8];
  const float* Wr_w = (const float*)d_in[9];
  const float* rwb  = (const float*)d_in[10];
  const float* rrb  = (const float*)d_in[11];
  const float* Wo_w = (const float*)d_in[12];
  const float* Wo_b = (const float*)d_in[13];

  char* ws = (char*)d_ws;
  const long MB = 1 << 20;
  __bf16* Wtq = (__bf16*)(ws + 0 * MB);
  __bf16* Wtk = (__bf16*)(ws + 2 * MB);
  __bf16* Wtv = (__bf16*)(ws + 4 * MB);
  __bf16* Wtr = (__bf16*)(ws + 6 * MB);
  __bf16* Wto = (__bf16*)(ws + 8 * MB);
  __bf16* qb  = (__bf16*)(ws + 10 * MB);
  __bf16* qrr = (__bf16*)(ws + 18 * MB);
  __bf16* kb  = (__bf16*)(ws + 26 * MB);
  __bf16* vt  = (__bf16*)(ws + 34 * MB);
  __bf16* rb  = (__bf16*)(ws + 42 * MB);
  float*  cb  = (float*)(ws + 46 * MB);
  float*  attn = (float*)(ws + 47 * MB);
  float*  scores = (float*)(ws + 63 * MB);

  int CH = 128;
  if (ws_size >= (size_t)(63 * MB) + 134217728ull) CH = 512;
  else if (ws_size >= (size_t)(63 * MB) + 67108864ull) CH = 256;
  const int nch = 2048 / CH;

  dim3 blk(256);

  tr_cvt<<<dim3(16, 16), blk, 0, stream>>>(Wq_w, Wtq);
  tr_cvt<<<dim3(16, 16), blk, 0, stream>>>(Wk_w, Wtk);
  tr_cvt<<<dim3(16, 16), blk, 0, stream>>>(Wv_w, Wtv);
  tr_cvt<<<dim3(16, 16), blk, 0, stream>>>(Wr_w, Wtr);
  tr_cvt<<<dim3(16, 16), blk, 0, stream>>>(Wo_w, Wto);

  GP p{};
  p.lda = 1024; p.ldb = 1024; p.K = 1024; p.sAz = 0; p.sBz = 0;
  p.scale = 1.f; p.lo = 0; p.CH = CH;

  // Q projection (writes q and q+r_r_bias, head-major)
  p.A = inputs_q; p.B = Wtq; p.out1 = qb; p.out2 = qrr; p.bias = Wq_b; p.rrb = rrb;
  gemm_k<0, true><<<dim3(8, 32, 1), blk, 0, stream>>>(p);
  // K projection
  p.A = inputs_kv; p.B = Wtk; p.out1 = kb; p.out2 = nullptr; p.bias = Wk_b;
  gemm_k<1, true><<<dim3(8, 32, 1), blk, 0, stream>>>(p);
  // V projection (transposed [bh][d][seq])
  p.A = inputs_kv; p.B = Wtv; p.out1 = vt; p.bias = Wv_b;
  gemm_k<2, true><<<dim3(8, 32, 1), blk, 0, stream>>>(p);
  // R projection (no bias)
  p.A = pos_embed; p.B = Wtr; p.out1 = rb; p.bias = nullptr;
  gemm_k<3, true><<<dim3(8, 16, 1), blk, 0, stream>>>(p);

  cb_k<<<dim3(256), blk, 0, stream>>>(kb, rwb, cb);
  hipMemsetAsync(attn, 0, (size_t)4096 * 1024 * 4, stream);

  for (int c = 0; c < nch; c++) {
    int lo = c * CH;
    // K1: scores = scale*(q k^T) + cb
    GP s{};
    s.A = (const void*)(qb + (long)lo * 64); s.B = kb;
    s.sAz = (long)2048 * 64; s.sBz = (long)2048 * 64;
    s.lda = 64; s.ldb = 64; s.K = 64;
    s.outF = scores; s.cbv = cb; s.scale = 0.125f; s.lo = lo; s.CH = CH;
    gemm_k<5, false><<<dim3(16, CH / 128, 32), blk, 0, stream>>>(s);
    // K2: scatter-add rel-shifted position bias
    s.A = (const void*)(qrr + (long)lo * 64); s.B = rb; s.cbv = nullptr;
    gemm_k<6, false><<<dim3(16, CH / 128, 32), blk, 0, stream>>>(s);
    if (lo + CH < 2048)
      pos_extra<<<dim3(8, 32), blk, 0, stream>>>(qrr, rb, scores, lo, CH);
    // K3: softmax (fp32, in place)
    softmax_k<<<dim3(32 * CH), blk, 0, stream>>>(scores);
    // K4: PV split-K, atomic accumulate into attn fp32
    pv_k<<<dim3(8, CH / 128, 32), blk, 0, stream>>>(scores, vt, attn, lo, CH);
  }

  // Output projection: d_out = attn @ Wo + bo (fp32 out)
  GP o{};
  o.A = attn; o.B = Wto; o.lda = 1024; o.ldb = 1024; o.K = 1024;
  o.sAz = 0; o.sBz = 0; o.bias = Wo_b; o.outF = (float*)d_out; o.CH = CH;
  gemm_k<4, true><<<dim3(8, 32, 1), blk, 0, stream>>>(o);
}

// Round 2
// 902.100 us; speedup vs baseline: 1.3725x; 1.3725x over previous
//
#include <hip/hip_runtime.h>

// RelMultiHeadAttention (Transformer-XL) on gfx950.
// B=2, S=2048, D=1024, H=16, hd=64. All heavy math in bf16 MFMA 16x16x32.
// R1: scores pipeline reworked — pos bias written unshifted (pure tile write),
// rel-shift applied as contiguous GATHER in softmax; qk/x/probs all bf16.

typedef float  floatx4 __attribute__((ext_vector_type(4)));
typedef __bf16 bf16x8  __attribute__((ext_vector_type(8)));

#define LSTR 40   // LDS row stride (bf16 elems): 80B rows -> conflict-free b128 reads

struct GP {
  const void* A;
  const __bf16* B;
  long sAz, sBz;         // batch (z) strides in elements
  int lda, ldb, K;
  float* outF;
  __bf16* out1;
  __bf16* out2;
  const float* bias;
  const float* rrb;
  const float* cbv;
  float scale;
  int lo, CH, ldout;
};

// MODE: 0=Qproj(dual q/qrr) 1=Kproj 2=Vproj(transposed) 3=Rproj 4=OUTproj
//       5=QK-scores(bf16 tile write, +cb)  7=POS x (bf16 tile write, B per-head)
template<int MODE, bool AF32>
__global__ void __launch_bounds__(256) gemm_k(GP p) {
  __shared__ __bf16 lA[128 * LSTR];
  __shared__ __bf16 lB[128 * LSTR];
  const int t = threadIdx.x;
  const int wave = t >> 6, lane = t & 63;
  const int z = blockIdx.z;
  const int m0 = blockIdx.y * 128, n0 = blockIdx.x * 128;
  const int srow = t >> 2, scol = (t & 3) << 3;

  const float*  Af = (const float*)p.A;
  const __bf16* Ab = (const __bf16*)p.A;
  const long aoff = (long)z * p.sAz;
  long boff;
  if constexpr (MODE == 7) boff = (long)(z & 15) * p.sBz;  // r is per-head only
  else                     boff = (long)z * p.sBz;
  const __bf16* Bb = p.B + boff;

  floatx4 acc[4][4];
#pragma unroll
  for (int i = 0; i < 4; i++)
#pragma unroll
    for (int j = 0; j < 4; j++) acc[i][j] = floatx4{0.f, 0.f, 0.f, 0.f};

  const int lr = lane & 15, lq = lane >> 4;
  const int wr = (wave >> 1) << 6, wc = (wave & 1) << 6;

  for (int kk = 0; kk < p.K; kk += 32) {
#pragma unroll
    for (int h2 = 0; h2 < 2; h2++) {
      int r = srow + (h2 << 6);
      if (AF32) {
        const float* ap = Af + aoff + (long)(m0 + r) * p.lda + kk + scol;
        float4 f0 = *(const float4*)ap;
        float4 f1 = *(const float4*)(ap + 4);
        bf16x8 o;
        o[0] = (__bf16)f0.x; o[1] = (__bf16)f0.y; o[2] = (__bf16)f0.z; o[3] = (__bf16)f0.w;
        o[4] = (__bf16)f1.x; o[5] = (__bf16)f1.y; o[6] = (__bf16)f1.z; o[7] = (__bf16)f1.w;
        *(bf16x8*)&lA[r * LSTR + scol] = o;
      } else {
        const __bf16* ap = Ab + aoff + (long)(m0 + r) * p.lda + kk + scol;
        *(bf16x8*)&lA[r * LSTR + scol] = *(const bf16x8*)ap;
      }
      const __bf16* bp = Bb + (long)(n0 + r) * p.ldb + kk + scol;
      *(bf16x8*)&lB[r * LSTR + scol] = *(const bf16x8*)bp;
    }
    __syncthreads();
    bf16x8 aF[4], bF[4];
#pragma unroll
    for (int i = 0; i < 4; i++)
      aF[i] = *(bf16x8*)&lA[(wr + i * 16 + lr) * LSTR + (lq << 3)];
#pragma unroll
    for (int i = 0; i < 4; i++)
      bF[i] = *(bf16x8*)&lB[(wc + i * 16 + lr) * LSTR + (lq << 3)];
#pragma unroll
    for (int i = 0; i < 4; i++)
#pragma unroll
      for (int j = 0; j < 4; j++)
        acc[i][j] = __builtin_amdgcn_mfma_f32_16x16x32_bf16(aF[i], bF[j], acc[i][j], 0, 0, 0);
    __syncthreads();
  }

  // Epilogue. C/D layout: col = lane&15, row = (lane>>4)*4 + reg  [measured m89/m91]
#pragma unroll
  for (int i = 0; i < 4; i++) {
#pragma unroll
    for (int j = 0; j < 4; j++) {
      int col = n0 + wc + j * 16 + lr;
#pragma unroll
      for (int g = 0; g < 4; g++) {
        int rl = m0 + wr + i * 16 + (lq << 2) + g;
        float val = acc[i][j][g];
        if constexpr (MODE <= 2) {
          int b = rl >> 11, s = rl & 2047;
          int h = col >> 6, d = col & 63;
          float v = val + p.bias[col];
          if constexpr (MODE == 0) {
            long dst = (((long)(b * 16 + h) * 2048 + s) << 6) + d;
            p.out1[dst] = (__bf16)v;
            p.out2[dst] = (__bf16)(v + p.rrb[col]);
          } else if constexpr (MODE == 1) {
            long dst = (((long)(b * 16 + h) * 2048 + s) << 6) + d;
            p.out1[dst] = (__bf16)v;
          } else {  // V transposed: [bh][d][seq]
            long dst = ((((long)(b * 16 + h)) << 6) + d) * 2048 + s;
            p.out1[dst] = (__bf16)v;
          }
        } else if constexpr (MODE == 3) {
          int h = col >> 6, d = col & 63;
          long dst = (((long)h * 2048 + rl) << 6) + d;
          p.out1[dst] = (__bf16)val;
        } else if constexpr (MODE == 4) {
          p.outF[(long)rl * 1024 + col] = val + p.bias[col];
        } else {  // 5 / 7: bf16 tile write, chunk-local row rl, row-stride ldout
          float v = val * p.scale;
          if (p.cbv) v += p.cbv[z * 2048 + col];
          p.out1[((long)z * p.ldout + rl) * 2048 + col] = (__bf16)v;
        }
      }
    }
  }
}

// boundary row a = lo+CH: write x[z][CH][m] = (qrr_a . r_m)*scale for m <= 2046-a
__global__ void __launch_bounds__(256) pos_extra2(const __bf16* qrr, const __bf16* rb,
                                                  __bf16* xb, int lo, int CH) {
  const int z = blockIdx.y;
  const int h = z & 15;
  const int a = lo + CH;
  __shared__ float qa[64];
  if (threadIdx.x < 64)
    qa[threadIdx.x] = (float)qrr[(((long)z * 2048 + a) << 6) + threadIdx.x];
  __syncthreads();
  int m = blockIdx.x * 256 + threadIdx.x;
  if (m <= 2046 - a) {
    const __bf16* rp = rb + (((long)h * 2048 + m) << 6);
    float s = 0.f;
#pragma unroll
    for (int c = 0; c < 8; c++) {
      bf16x8 rv = *(const bf16x8*)(rp + c * 8);
#pragma unroll
      for (int e = 0; e < 8; e++) s += qa[c * 8 + e] * (float)rv[e];
    }
    xb[((long)z * (CH + 1) + CH) * 2048 + m] = (__bf16)(s * 0.125f);
  }
}

__global__ void __launch_bounds__(256) cb_k(const __bf16* kb, const float* rwb, float* cb) {
  long id = (long)blockIdx.x * 256 + threadIdx.x;  // 32*2048
  int z = (int)(id >> 11);
  int j = (int)(id & 2047);
  int h = z & 15;
  const __bf16* kp = kb + (((long)z * 2048 + j) << 6);
  float s = 0.f;
#pragma unroll
  for (int c = 0; c < 8; c++) {
    bf16x8 kv = *(const bf16x8*)(kp + c * 8);
#pragma unroll
    for (int e = 0; e < 8; e++) s += rwb[h * 64 + c * 8 + e] * (float)kv[e];
  }
  cb[id] = s * 0.125f;
}

__global__ void __launch_bounds__(256) tr_cvt(const float* src, __bf16* dst) {
  __shared__ float tile[64][65];
  int bx = blockIdx.x, by = blockIdx.y;
  int tx = threadIdx.x & 63, ty = threadIdx.x >> 6;
#pragma unroll
  for (int r = ty; r < 64; r += 4)
    tile[r][tx] = src[(long)(by * 64 + r) * 1024 + bx * 64 + tx];
  __syncthreads();
#pragma unroll
  for (int r = ty; r < 64; r += 4)
    dst[(long)(bx * 64 + r) * 1024 + by * 64 + tx] = (__bf16)tile[tx][r];
}

// Gather rel-shifted pos bias, combine with qk+cb, softmax (fp32), write probs bf16 in place.
// grid: (CH rows, 32 z), 256 threads, 8 cols/thread.
__global__ void __launch_bounds__(256) smx_k(__bf16* qk, const __bf16* xb, int lo, int CH) {
  const int rr = blockIdx.x;
  const int z  = blockIdx.y;
  const int i  = lo + rr;
  __bf16* qrow = qk + ((long)z * CH + rr) * 2048;
  const __bf16* x0 = xb + ((long)z * (CH + 1) + rr) * 2048;  // row a=i
  const __bf16* x1 = x0 + 2048;                              // row a=i+1
  const int t = threadIdx.x;

  bf16x8 qv = *(const bf16x8*)(qrow + t * 8);
  float s[8];
#pragma unroll
  for (int e = 0; e < 8; e++) {
    int j = t * 8 + e;
    float pos;
    if (j <= i)            pos = (float)x0[2047 - i + j];   // case1 (contiguous in j)
    else if (j == i + 1)   pos = 0.f;
    else                   pos = (float)x1[j - i - 2];      // case2 (contiguous in j)
    s[e] = (float)qv[e] + pos;
  }
  float mx = s[0];
#pragma unroll
  for (int e = 1; e < 8; e++) mx = fmaxf(mx, s[e]);
#pragma unroll
  for (int o = 32; o > 0; o >>= 1) mx = fmaxf(mx, __shfl_down(mx, o, 64));
  __shared__ float red[4], red2[4];
  if ((t & 63) == 0) red[t >> 6] = mx;
  __syncthreads();
  mx = fmaxf(fmaxf(red[0], red[1]), fmaxf(red[2], red[3]));
  float sum = 0.f;
#pragma unroll
  for (int e = 0; e < 8; e++) { s[e] = __expf(s[e] - mx); sum += s[e]; }
#pragma unroll
  for (int o = 32; o > 0; o >>= 1) sum += __shfl_down(sum, o, 64);
  if ((t & 63) == 0) red2[t >> 6] = sum;
  __syncthreads();
  sum = red2[0] + red2[1] + red2[2] + red2[3];
  float inv = 1.0f / sum;
  bf16x8 pv;
#pragma unroll
  for (int e = 0; e < 8; e++) pv[e] = (__bf16)(s[e] * inv);
  *(bf16x8*)(qrow + t * 8) = pv;
}

// PV: attn[b, lo+i, h*64+d] += probs[z,i,:] @ v[z,:,d], split-K over `split` segs of Kseg
__global__ void __launch_bounds__(256) pv_k(const __bf16* probs, const __bf16* vt,
                                            float* attn, int lo, int CH, int Kseg) {
  __shared__ __bf16 lA[128 * LSTR];
  __shared__ __bf16 lB[64 * LSTR];
  const int t = threadIdx.x;
  const int wave = t >> 6, lane = t & 63;
  const int z = blockIdx.z;
  const int seg = blockIdx.x;
  const int m0 = blockIdx.y * 128;
  const int b = z >> 4, h = z & 15;
  const int srow = t >> 2, scol = (t & 3) << 3;
  const __bf16* A = probs + ((long)z * CH + m0) * 2048 + seg * Kseg;
  const __bf16* B = vt + ((long)z << 6) * 2048 + seg * Kseg;

  floatx4 acc[2][4];
#pragma unroll
  for (int i = 0; i < 2; i++)
#pragma unroll
    for (int j = 0; j < 4; j++) acc[i][j] = floatx4{0.f, 0.f, 0.f, 0.f};

  const int lr = lane & 15, lq = lane >> 4;
  const int wr = wave << 5;

  for (int kk = 0; kk < Kseg; kk += 32) {
#pragma unroll
    for (int h2 = 0; h2 < 2; h2++) {
      int r = srow + (h2 << 6);
      *(bf16x8*)&lA[r * LSTR + scol] = *(const bf16x8*)(A + (long)r * 2048 + kk + scol);
    }
    *(bf16x8*)&lB[srow * LSTR + scol] = *(const bf16x8*)(B + (long)srow * 2048 + kk + scol);
    __syncthreads();
    bf16x8 aF[2], bF[4];
#pragma unroll
    for (int i = 0; i < 2; i++)
      aF[i] = *(bf16x8*)&lA[(wr + i * 16 + lr) * LSTR + (lq << 3)];
#pragma unroll
    for (int j = 0; j < 4; j++)
      bF[j] = *(bf16x8*)&lB[(j * 16 + lr) * LSTR + (lq << 3)];
#pragma unroll
    for (int i = 0; i < 2; i++)
#pragma unroll
      for (int j = 0; j < 4; j++)
        acc[i][j] = __builtin_amdgcn_mfma_f32_16x16x32_bf16(aF[i], bF[j], acc[i][j], 0, 0, 0);
    __syncthreads();
  }
#pragma unroll
  for (int i = 0; i < 2; i++)
#pragma unroll
    for (int j = 0; j < 4; j++)
#pragma unroll
      for (int g = 0; g < 4; g++) {
        int rl = m0 + wr + i * 16 + (lq << 2) + g;
        int col = j * 16 + lr;
        unsafeAtomicAdd(&attn[((long)b * 2048 + lo + rl) * 1024 + h * 64 + col],
                        acc[i][j][g]);
      }
}

extern "C" void kernel_launch(void* const* d_in, const int* in_sizes, int n_in,
                              void* d_out, int out_size, void* d_ws, size_t ws_size,
                              hipStream_t stream) {
  (void)in_sizes; (void)n_in; (void)out_size;
  const float* inputs_kv = (const float*)d_in[0];
  const float* inputs_q  = (const float*)d_in[1];
  const float* pos_embed = (const float*)d_in[2];
  const float* Wq_w = (const float*)d_in[3];
  const float* Wq_b = (const float*)d_in[4];
  const float* Wk_w = (const float*)d_in[5];
  const float* Wk_b = (const float*)d_in[6];
  const float* Wv_w = (const float*)d_in[7];
  const float* Wv_b = (const float*)d_in[8];
  const float* Wr_w = (const float*)d_in[9];
  const float* rwb  = (const float*)d_in[10];
  const float* rrb  = (const float*)d_in[11];
  const float* Wo_w = (const float*)d_in[12];
  const float* Wo_b = (const float*)d_in[13];

  char* ws = (char*)d_ws;
  const long MB = 1 << 20;
  __bf16* Wtq = (__bf16*)(ws + 0 * MB);
  __bf16* Wtk = (__bf16*)(ws + 2 * MB);
  __bf16* Wtv = (__bf16*)(ws + 4 * MB);
  __bf16* Wtr = (__bf16*)(ws + 6 * MB);
  __bf16* Wto = (__bf16*)(ws + 8 * MB);
  __bf16* qb  = (__bf16*)(ws + 10 * MB);
  __bf16* qrr = (__bf16*)(ws + 18 * MB);
  __bf16* kb  = (__bf16*)(ws + 26 * MB);
  __bf16* vt  = (__bf16*)(ws + 34 * MB);
  __bf16* rb  = (__bf16*)(ws + 42 * MB);
  float*  cb  = (float*)(ws + 46 * MB);           // 256 KB
  float*  attn = (float*)(ws + 46 * MB + 256 * 1024);  // 16 MB
  char*   dynbase = ws + 62 * MB + 256 * 1024;

  // choose CH: need 32*CH*2048*2 (qk) + 32*(CH+1)*2048*2 (x) past dynbase
  size_t base = (size_t)(62 * MB + 256 * 1024);
  int CH = 128;
  if (ws_size >= base + (size_t)32 * 512 * 2048 * 2 + (size_t)32 * 513 * 2048 * 2) CH = 512;
  else if (ws_size >= base + (size_t)32 * 256 * 2048 * 2 + (size_t)32 * 257 * 2048 * 2) CH = 256;
  const int nch = 2048 / CH;
  const int split = 1024 / CH;          // pv split-K segments
  const int Kseg = 2048 / split;
  __bf16* qkbuf = (__bf16*)dynbase;
  __bf16* xbuf  = (__bf16*)(dynbase + (size_t)32 * CH * 2048 * 2);

  dim3 blk(256);

  tr_cvt<<<dim3(16, 16), blk, 0, stream>>>(Wq_w, Wtq);
  tr_cvt<<<dim3(16, 16), blk, 0, stream>>>(Wk_w, Wtk);
  tr_cvt<<<dim3(16, 16), blk, 0, stream>>>(Wv_w, Wtv);
  tr_cvt<<<dim3(16, 16), blk, 0, stream>>>(Wr_w, Wtr);
  tr_cvt<<<dim3(16, 16), blk, 0, stream>>>(Wo_w, Wto);

  GP p{};
  p.lda = 1024; p.ldb = 1024; p.K = 1024; p.sAz = 0; p.sBz = 0;
  p.scale = 1.f; p.lo = 0; p.CH = CH;

  // Q projection (writes q and q+r_r_bias, head-major)
  p.A = inputs_q; p.B = Wtq; p.out1 = qb; p.out2 = qrr; p.bias = Wq_b; p.rrb = rrb;
  gemm_k<0, true><<<dim3(8, 32, 1), blk, 0, stream>>>(p);
  // K projection
  p.A = inputs_kv; p.B = Wtk; p.out1 = kb; p.out2 = nullptr; p.bias = Wk_b;
  gemm_k<1, true><<<dim3(8, 32, 1), blk, 0, stream>>>(p);
  // V projection (transposed [bh][d][seq])
  p.A = inputs_kv; p.B = Wtv; p.out1 = vt; p.bias = Wv_b;
  gemm_k<2, true><<<dim3(8, 32, 1), blk, 0, stream>>>(p);
  // R projection (no bias)
  p.A = pos_embed; p.B = Wtr; p.out1 = rb; p.bias = nullptr;
  gemm_k<3, true><<<dim3(8, 16, 1), blk, 0, stream>>>(p);

  cb_k<<<dim3(256), blk, 0, stream>>>(kb, rwb, cb);
  hipMemsetAsync(attn, 0, (size_t)4096 * 1024 * 4, stream);

  for (int c = 0; c < nch; c++) {
    int lo = c * CH;
    // K1: qkbuf = bf16( scale*(q k^T) + cb )
    GP s{};
    s.A = (const void*)(qb + (long)lo * 64); s.B = kb;
    s.sAz = (long)2048 * 64; s.sBz = (long)2048 * 64;
    s.lda = 64; s.ldb = 64; s.K = 64;
    s.out1 = qkbuf; s.cbv = cb; s.scale = 0.125f; s.lo = lo; s.CH = CH; s.ldout = CH;
    gemm_k<5, false><<<dim3(16, CH / 128, 32), blk, 0, stream>>>(s);
    // K2: xbuf = bf16( scale * (qrr r^T) ), unshifted tile write
    s.A = (const void*)(qrr + (long)lo * 64); s.B = rb; s.cbv = nullptr;
    s.out1 = xbuf; s.ldout = CH + 1;
    gemm_k<7, false><<<dim3(16, CH / 128, 32), blk, 0, stream>>>(s);
    if (lo + CH < 2048)
      pos_extra2<<<dim3(8, 32), blk, 0, stream>>>(qrr, rb, xbuf, lo, CH);
    // K3: gather rel-shift + combine + softmax -> probs bf16 in place
    smx_k<<<dim3(CH, 32), blk, 0, stream>>>(qkbuf, xbuf, lo, CH);
    // K4: PV split-K, atomic accumulate into attn fp32
    pv_k<<<dim3(split, CH / 128, 32), blk, 0, stream>>>(qkbuf, vt, attn, lo, CH, Kseg);
  }

  // Output projection: d_out = attn @ Wo + bo (fp32 out)
  GP o{};
  o.A = attn; o.B = Wto; o.lda = 1024; o.ldb = 1024; o.K = 1024;
  o.sAz = 0; o.sBz = 0; o.bias = Wo_b; o.outF = (float*)d_out; o.CH = CH;
  gemm_k<4, true><<<dim3(8, 32, 1), blk, 0, stream>>>(o);
}